// Round 1
// baseline (258.158 us; speedup 1.0000x reference)
//
#include <hip/hip_runtime.h>

// MHA: B=4, S=2048, D_MODEL=512, H=8, D_HEAD=64
// Pipeline: Wt transpose (fp32->bf16) -> QKV proj GEMMs (bf16 MFMA) ->
//           flash attention (bf16 MFMA, online softmax) -> out proj GEMM (fp32 out)

typedef unsigned short u16;
typedef __bf16 bf16x8 __attribute__((ext_vector_type(8)));
typedef float  f32x4  __attribute__((ext_vector_type(4)));

__device__ __forceinline__ u16 f2bf(float x) {
  unsigned u = __float_as_uint(x);
  u += 0x7fffu + ((u >> 16) & 1u);   // RNE
  return (u16)(u >> 16);
}

__device__ __forceinline__ f32x4 mfma16(bf16x8 a, bf16x8 b, f32x4 c) {
  return __builtin_amdgcn_mfma_f32_16x16x32_bf16(a, b, c, 0, 0, 0);
}

// ---- kernel 0: W[k][n] fp32 -> Wt[n][k] bf16 (512x512) ----
__global__ __launch_bounds__(256) void wtrans_k(const float* __restrict__ W,
                                                u16* __restrict__ Wt) {
  int idx = blockIdx.x * 256 + threadIdx.x;   // 0..262143
  int k = idx >> 9, n = idx & 511;
  Wt[n * 512 + k] = f2bf(W[idx]);
}

// ---- GEMM: A[8192x512] @ B[512x512] + bias.  Bt is [n][k] bf16. ----
// A_BF16: A is bf16 (else fp32, converted in staging)
// OUT_MODE: 0 = bf16 row-major [m][n], 1 = bf16 transposed vT[(b*8+h)*64+d][s], 2 = fp32 row-major
template <bool A_BF16, int OUT_MODE>
__global__ __launch_bounds__(256) void gemm_k(const void* __restrict__ Ap,
                                              const u16* __restrict__ Bt,
                                              const float* __restrict__ bias,
                                              void* __restrict__ outp) {
  // 128x128 tile, BK=64, 4 waves in 2x2, each wave 64x64 via 4x4 16x16x32 MFMA frags.
  __shared__ __align__(16) u16 As[128][72];   // [m][k], pad 64->72 (stride 144B: 4-bank shift/row)
  __shared__ __align__(16) u16 Bs[128][72];   // [n][k]
  int tid = threadIdx.x;
  int lane = tid & 63, wid = tid >> 6;
  int wm = wid >> 1, wn = wid & 1;
  int lr = lane & 15, lg = lane >> 4;
  int bm = blockIdx.x >> 2, bn = blockIdx.x & 3;

  f32x4 acc[4][4];
#pragma unroll
  for (int i = 0; i < 4; ++i)
#pragma unroll
    for (int j = 0; j < 4; ++j) {
      f32x4 z = {0.f, 0.f, 0.f, 0.f};
      acc[i][j] = z;
    }

  for (int kt = 0; kt < 8; ++kt) {
    int k0 = kt * 64;
    if (!A_BF16) {
      const float* A = (const float*)Ap;
#pragma unroll
      for (int i = 0; i < 8; ++i) {
        int idx = i * 256 + tid;          // 2048 float4 chunks
        int row = idx >> 4, c4 = idx & 15;
        float4 v = *(const float4*)(A + (size_t)(bm * 128 + row) * 512 + k0 + c4 * 4);
        ushort4 pk = make_ushort4(f2bf(v.x), f2bf(v.y), f2bf(v.z), f2bf(v.w));
        *(ushort4*)&As[row][c4 * 4] = pk;
      }
    } else {
      const u16* A = (const u16*)Ap;
#pragma unroll
      for (int i = 0; i < 4; ++i) {
        int idx = i * 256 + tid;          // 1024 16B chunks
        int row = idx >> 3, c8 = idx & 7;
        uint4 v = *(const uint4*)(A + (size_t)(bm * 128 + row) * 512 + k0 + c8 * 8);
        *(uint4*)&As[row][c8 * 8] = v;
      }
    }
#pragma unroll
    for (int i = 0; i < 4; ++i) {
      int idx = i * 256 + tid;
      int row = idx >> 3, c8 = idx & 7;
      uint4 v = *(const uint4*)(Bt + (size_t)(bn * 128 + row) * 512 + k0 + c8 * 8);
      *(uint4*)&Bs[row][c8 * 8] = v;
    }
    __syncthreads();
#pragma unroll
    for (int kk = 0; kk < 2; ++kk) {
      bf16x8 af[4], bfr[4];
#pragma unroll
      for (int mf = 0; mf < 4; ++mf)
        af[mf] = *(const bf16x8*)&As[wm * 64 + mf * 16 + lr][kk * 32 + lg * 8];
#pragma unroll
      for (int nf = 0; nf < 4; ++nf)
        bfr[nf] = *(const bf16x8*)&Bs[wn * 64 + nf * 16 + lr][kk * 32 + lg * 8];
#pragma unroll
      for (int mf = 0; mf < 4; ++mf)
#pragma unroll
        for (int nf = 0; nf < 4; ++nf)
          acc[mf][nf] = mfma16(af[mf], bfr[nf], acc[mf][nf]);
    }
    __syncthreads();
  }

  // epilogue: D[row=(lg*4+r)][col=lr] per 16x16 frag (m89-verified layout)
#pragma unroll
  for (int mf = 0; mf < 4; ++mf) {
#pragma unroll
    for (int nf = 0; nf < 4; ++nf) {
      int m = bm * 128 + wm * 64 + mf * 16 + lg * 4;
      int n = bn * 128 + wn * 64 + nf * 16 + lr;
      float bia = bias[n];
      if (OUT_MODE == 0) {
        u16* o = (u16*)outp;
#pragma unroll
        for (int r = 0; r < 4; ++r)
          o[(size_t)(m + r) * 512 + n] = f2bf(acc[mf][nf][r] + bia);
      } else if (OUT_MODE == 2) {
        float* o = (float*)outp;
#pragma unroll
        for (int r = 0; r < 4; ++r)
          o[(size_t)(m + r) * 512 + n] = acc[mf][nf][r] + bia;
      } else {
        // vT[(b*8+h)*64 + d][s]; m = b*2048+s, n = h*64+d; 4 consecutive s per lane -> 8B store
        u16* o = (u16*)outp;
        int b = m >> 11, s = m & 2047;
        int h = n >> 6, d = n & 63;
        ushort4 pk = make_ushort4(f2bf(acc[mf][nf][0] + bia), f2bf(acc[mf][nf][1] + bia),
                                  f2bf(acc[mf][nf][2] + bia), f2bf(acc[mf][nf][3] + bia));
        *(ushort4*)&o[(size_t)((b * 8 + h) * 64 + d) * 2048 + s] = pk;
      }
    }
  }
}

// ---- flash attention: q,k bf16 [B*S][512]; vT bf16 [(b*8+h)*64+d][2048]; z bf16 [B*S][512] ----
__global__ __launch_bounds__(256) void attn_k(const u16* __restrict__ q,
                                              const u16* __restrict__ kmat,
                                              const u16* __restrict__ vT,
                                              u16* __restrict__ z) {
  __shared__ __align__(16) u16 Ks[64][72];       // [key][d]
  __shared__ __align__(16) u16 Vs[64][72];       // [d][key]
  __shared__ __align__(16) u16 Ps[4][32][72];    // per-wave P [qrow][key]
  const float C = 0.125f * 1.44269504f;          // 1/sqrt(64) * log2(e)
  int tid = threadIdx.x;
  int lane = tid & 63, w = tid >> 6;
  int lr = lane & 15, lg = lane >> 4;
  int bh = blockIdx.x >> 4, qt = blockIdx.x & 15;
  int b = bh >> 3, h = bh & 7;
  size_t qrow0 = (size_t)(b * 2048 + qt * 128 + w * 32);

  // Q fragments in registers: wave owns 32 q-rows
  bf16x8 qf[2][2];
#pragma unroll
  for (int mf = 0; mf < 2; ++mf)
#pragma unroll
    for (int kf = 0; kf < 2; ++kf)
      qf[mf][kf] = *(const bf16x8*)&q[(qrow0 + mf * 16 + lr) * 512 + h * 64 + kf * 32 + lg * 8];

  f32x4 oacc[2][4];
#pragma unroll
  for (int i = 0; i < 2; ++i)
#pragma unroll
    for (int j = 0; j < 4; ++j) {
      f32x4 zf = {0.f, 0.f, 0.f, 0.f};
      oacc[i][j] = zf;
    }
  float mrow[2][4], lrow[2][4];
#pragma unroll
  for (int i = 0; i < 2; ++i)
#pragma unroll
    for (int r = 0; r < 4; ++r) { mrow[i][r] = -1e30f; lrow[i][r] = 0.f; }

  for (int kt = 0; kt < 32; ++kt) {
    // stage K tile [64 keys][64 d] and V tile [64 d][64 keys]
#pragma unroll
    for (int i = 0; i < 2; ++i) {
      int idx = i * 256 + tid;
      int row = idx >> 3, c8 = idx & 7;
      *(uint4*)&Ks[row][c8 * 8] =
          *(const uint4*)&kmat[(size_t)(b * 2048 + kt * 64 + row) * 512 + h * 64 + c8 * 8];
      *(uint4*)&Vs[row][c8 * 8] =
          *(const uint4*)&vT[(size_t)(bh * 64 + row) * 2048 + kt * 64 + c8 * 8];
    }
    __syncthreads();

    // S = Q @ K^T  (raw scores; scale folded into exp)
    f32x4 sacc[2][4];
#pragma unroll
    for (int i = 0; i < 2; ++i)
#pragma unroll
      for (int j = 0; j < 4; ++j) {
        f32x4 zf = {0.f, 0.f, 0.f, 0.f};
        sacc[i][j] = zf;
      }
#pragma unroll
    for (int kf = 0; kf < 2; ++kf) {
      bf16x8 kb[4];
#pragma unroll
      for (int nf = 0; nf < 4; ++nf)
        kb[nf] = *(const bf16x8*)&Ks[nf * 16 + lr][kf * 32 + lg * 8];
#pragma unroll
      for (int mf = 0; mf < 2; ++mf)
#pragma unroll
        for (int nf = 0; nf < 4; ++nf)
          sacc[mf][nf] = mfma16(qf[mf][kf], kb[nf], sacc[mf][nf]);
    }

    // online softmax: row stats live in the 16-lane group holding that row
#pragma unroll
    for (int mf = 0; mf < 2; ++mf) {
#pragma unroll
      for (int r = 0; r < 4; ++r) {
        float mx = fmaxf(fmaxf(sacc[mf][0][r], sacc[mf][1][r]),
                         fmaxf(sacc[mf][2][r], sacc[mf][3][r]));
        mx = fmaxf(mx, __shfl_xor(mx, 1));
        mx = fmaxf(mx, __shfl_xor(mx, 2));
        mx = fmaxf(mx, __shfl_xor(mx, 4));
        mx = fmaxf(mx, __shfl_xor(mx, 8));
        float mnew = fmaxf(mrow[mf][r], mx);
        float sc = exp2f((mrow[mf][r] - mnew) * C);
        mrow[mf][r] = mnew;
        float rsum = 0.f;
#pragma unroll
        for (int nf = 0; nf < 4; ++nf) {
          float p = exp2f((sacc[mf][nf][r] - mnew) * C);
          sacc[mf][nf][r] = p;
          rsum += p;
        }
        rsum += __shfl_xor(rsum, 1);
        rsum += __shfl_xor(rsum, 2);
        rsum += __shfl_xor(rsum, 4);
        rsum += __shfl_xor(rsum, 8);
        lrow[mf][r] = lrow[mf][r] * sc + rsum;
#pragma unroll
        for (int nfo = 0; nfo < 4; ++nfo) oacc[mf][nfo][r] *= sc;
      }
      // P -> wave-private LDS, [qrow][key] so PV A-frags are contiguous-k
#pragma unroll
      for (int nf = 0; nf < 4; ++nf)
#pragma unroll
        for (int r = 0; r < 4; ++r)
          Ps[w][mf * 16 + lg * 4 + r][nf * 16 + lr] = f2bf(sacc[mf][nf][r]);
    }

    // O += P @ V
#pragma unroll
    for (int ks = 0; ks < 2; ++ks) {
      bf16x8 pa[2], vb[4];
#pragma unroll
      for (int mf = 0; mf < 2; ++mf)
        pa[mf] = *(const bf16x8*)&Ps[w][mf * 16 + lr][ks * 32 + lg * 8];
#pragma unroll
      for (int nfo = 0; nfo < 4; ++nfo)
        vb[nfo] = *(const bf16x8*)&Vs[nfo * 16 + lr][ks * 32 + lg * 8];
#pragma unroll
      for (int mf = 0; mf < 2; ++mf)
#pragma unroll
        for (int nfo = 0; nfo < 4; ++nfo)
          oacc[mf][nfo] = mfma16(pa[mf], vb[nfo], oacc[mf][nfo]);
    }
    __syncthreads();
  }

  // normalize + store z (bf16, [B*S][512])
#pragma unroll
  for (int mf = 0; mf < 2; ++mf)
#pragma unroll
    for (int nfo = 0; nfo < 4; ++nfo)
#pragma unroll
      for (int r = 0; r < 4; ++r) {
        float o = oacc[mf][nfo][r] / lrow[mf][r];
        z[(qrow0 + mf * 16 + lg * 4 + r) * 512 + h * 64 + nfo * 16 + lr] = f2bf(o);
      }
}

extern "C" void kernel_launch(void* const* d_in, const int* in_sizes, int n_in,
                              void* d_out, int out_size, void* d_ws, size_t ws_size,
                              hipStream_t stream) {
  const float* Q  = (const float*)d_in[0];
  const float* K  = (const float*)d_in[1];
  const float* V  = (const float*)d_in[2];
  const float* Wq = (const float*)d_in[3];
  const float* bq = (const float*)d_in[4];
  const float* Wk = (const float*)d_in[5];
  const float* bk = (const float*)d_in[6];
  const float* Wv = (const float*)d_in[7];
  const float* bv = (const float*)d_in[8];
  const float* Wo = (const float*)d_in[9];
  const float* bo = (const float*)d_in[10];
  float* out = (float*)d_out;

  // workspace layout (34 MB total, all bf16/u16):
  u16* ws  = (u16*)d_ws;
  u16* Wtq = ws;                                   // 512*512 each
  u16* Wtk = Wtq + 512 * 512;
  u16* Wtv = Wtk + 512 * 512;
  u16* Wto = Wtv + 512 * 512;
  u16* qws = Wto + 512 * 512;                      // 8192*512 each
  u16* kws = qws + (size_t)8192 * 512;
  u16* vTw = kws + (size_t)8192 * 512;             // [(b*8+h)*64+d][2048]
  u16* zws = vTw + (size_t)8192 * 512;

  wtrans_k<<<1024, 256, 0, stream>>>(Wq, Wtq);
  wtrans_k<<<1024, 256, 0, stream>>>(Wk, Wtk);
  wtrans_k<<<1024, 256, 0, stream>>>(Wv, Wtv);
  wtrans_k<<<1024, 256, 0, stream>>>(Wo, Wto);

  gemm_k<false, 0><<<256, 256, 0, stream>>>(Q, Wtq, bq, qws);
  gemm_k<false, 0><<<256, 256, 0, stream>>>(K, Wtk, bk, kws);
  gemm_k<false, 1><<<256, 256, 0, stream>>>(V, Wtv, bv, vTw);

  attn_k<<<512, 256, 0, stream>>>(qws, kws, vTw, zws);

  gemm_k<true, 2><<<256, 256, 0, stream>>>(zws, Wto, bo, out);
}

// Round 2
// 199.758 us; speedup vs baseline: 1.2924x; 1.2924x over previous
//
#include <hip/hip_runtime.h>

// MHA: B=4, S=2048, D_MODEL=512, H=8, D_HEAD=64
// Pipeline: Wt transpose (fp32->bf16) -> QKV proj GEMMs (bf16 MFMA) ->
//           flash attention (bf16 MFMA, online softmax) -> out proj GEMM (fp32 out)

typedef unsigned short u16;
typedef __bf16 bf16x8 __attribute__((ext_vector_type(8)));
typedef float  f32x4  __attribute__((ext_vector_type(4)));

__device__ __forceinline__ u16 f2bf(float x) {
  unsigned u = __float_as_uint(x);
  u += 0x7fffu + ((u >> 16) & 1u);   // RNE
  return (u16)(u >> 16);
}

__device__ __forceinline__ f32x4 mfma16(bf16x8 a, bf16x8 b, f32x4 c) {
  return __builtin_amdgcn_mfma_f32_16x16x32_bf16(a, b, c, 0, 0, 0);
}

// ---- kernel 0: W[k][n] fp32 -> Wt[n][k] bf16 (512x512) ----
__global__ __launch_bounds__(256) void wtrans_k(const float* __restrict__ W,
                                                u16* __restrict__ Wt) {
  int idx = blockIdx.x * 256 + threadIdx.x;   // 0..262143
  int k = idx >> 9, n = idx & 511;
  Wt[n * 512 + k] = f2bf(W[idx]);
}

// ---- GEMM: A[8192x512] @ B[512x512] + bias.  Bt is [n][k] bf16. ----
// OUT_MODE: 0 = bf16 row-major [m][n], 1 = bf16 transposed vT[(b*8+h)*64+d][s], 2 = fp32 row-major
template <bool A_BF16, int OUT_MODE>
__global__ __launch_bounds__(256) void gemm_k(const void* __restrict__ Ap,
                                              const u16* __restrict__ Bt,
                                              const float* __restrict__ bias,
                                              void* __restrict__ outp) {
  // 128x128 tile, BK=64, 4 waves in 2x2, each wave 64x64 via 4x4 16x16x32 MFMA frags.
  __shared__ __align__(16) u16 As[128][72];   // [m][k]
  __shared__ __align__(16) u16 Bs[128][72];   // [n][k]
  int tid = threadIdx.x;
  int lane = tid & 63, wid = tid >> 6;
  int wm = wid >> 1, wn = wid & 1;
  int lr = lane & 15, lg = lane >> 4;
  int bm = blockIdx.x >> 2, bn = blockIdx.x & 3;

  f32x4 acc[4][4];
#pragma unroll
  for (int i = 0; i < 4; ++i)
#pragma unroll
    for (int j = 0; j < 4; ++j) {
      f32x4 z = {0.f, 0.f, 0.f, 0.f};
      acc[i][j] = z;
    }

  for (int kt = 0; kt < 8; ++kt) {
    int k0 = kt * 64;
    if (!A_BF16) {
      const float* A = (const float*)Ap;
#pragma unroll
      for (int i = 0; i < 8; ++i) {
        int idx = i * 256 + tid;          // 2048 float4 chunks
        int row = idx >> 4, c4 = idx & 15;
        float4 v = *(const float4*)(A + (size_t)(bm * 128 + row) * 512 + k0 + c4 * 4);
        ushort4 pk = make_ushort4(f2bf(v.x), f2bf(v.y), f2bf(v.z), f2bf(v.w));
        *(ushort4*)&As[row][c4 * 4] = pk;
      }
    } else {
      const u16* A = (const u16*)Ap;
#pragma unroll
      for (int i = 0; i < 4; ++i) {
        int idx = i * 256 + tid;          // 1024 16B chunks
        int row = idx >> 3, c8 = idx & 7;
        uint4 v = *(const uint4*)(A + (size_t)(bm * 128 + row) * 512 + k0 + c8 * 8);
        *(uint4*)&As[row][c8 * 8] = v;
      }
    }
#pragma unroll
    for (int i = 0; i < 4; ++i) {
      int idx = i * 256 + tid;
      int row = idx >> 3, c8 = idx & 7;
      uint4 v = *(const uint4*)(Bt + (size_t)(bn * 128 + row) * 512 + k0 + c8 * 8);
      *(uint4*)&Bs[row][c8 * 8] = v;
    }
    __syncthreads();
#pragma unroll
    for (int kk = 0; kk < 2; ++kk) {
      bf16x8 af[4], bfr[4];
#pragma unroll
      for (int mf = 0; mf < 4; ++mf)
        af[mf] = *(const bf16x8*)&As[wm * 64 + mf * 16 + lr][kk * 32 + lg * 8];
#pragma unroll
      for (int nf = 0; nf < 4; ++nf)
        bfr[nf] = *(const bf16x8*)&Bs[wn * 64 + nf * 16 + lr][kk * 32 + lg * 8];
#pragma unroll
      for (int mf = 0; mf < 4; ++mf)
#pragma unroll
        for (int nf = 0; nf < 4; ++nf)
          acc[mf][nf] = mfma16(af[mf], bfr[nf], acc[mf][nf]);
    }
    __syncthreads();
  }

  // epilogue: D[row=(lg*4+r)][col=lr] per 16x16 frag (m89-verified layout)
#pragma unroll
  for (int mf = 0; mf < 4; ++mf) {
#pragma unroll
    for (int nf = 0; nf < 4; ++nf) {
      int m = bm * 128 + wm * 64 + mf * 16 + lg * 4;
      int n = bn * 128 + wn * 64 + nf * 16 + lr;
      float bia = bias[n];
      if (OUT_MODE == 0) {
        u16* o = (u16*)outp;
#pragma unroll
        for (int r = 0; r < 4; ++r)
          o[(size_t)(m + r) * 512 + n] = f2bf(acc[mf][nf][r] + bia);
      } else if (OUT_MODE == 2) {
        float* o = (float*)outp;
#pragma unroll
        for (int r = 0; r < 4; ++r)
          o[(size_t)(m + r) * 512 + n] = acc[mf][nf][r] + bia;
      } else {
        // vT[(b*8+h)*64 + d][s]; m = b*2048+s, n = h*64+d; 4 consecutive s per lane -> 8B store
        u16* o = (u16*)outp;
        int b = m >> 11, s = m & 2047;
        int h = n >> 6, d = n & 63;
        ushort4 pk = make_ushort4(f2bf(acc[mf][nf][0] + bia), f2bf(acc[mf][nf][1] + bia),
                                  f2bf(acc[mf][nf][2] + bia), f2bf(acc[mf][nf][3] + bia));
        *(ushort4*)&o[(size_t)((b * 8 + h) * 64 + d) * 2048 + s] = pk;
      }
    }
  }
}

// ---- flash attention ----
// q,k bf16 [B*S][512]; vT bf16 [(b*8+h)*64+d][2048]; z bf16 [B*S][512]
// Grid: 32 bh * 32 qtiles = 1024 blocks (4/CU), 4 waves, 16 q-rows/wave, KVBLK=64.
// All LDS tiles are [row][64] u16 (128B rows -> bank-invariant) with 16B-granule
// XOR swizzle col ^ ((row&7)<<3) applied at write AND read (T2 / G4, m214 case).
__global__ __launch_bounds__(256) void attn_k(const u16* __restrict__ q,
                                              const u16* __restrict__ kmat,
                                              const u16* __restrict__ vT,
                                              u16* __restrict__ z) {
  __shared__ __align__(16) u16 Ks[64][64];       // [key][d]
  __shared__ __align__(16) u16 Vs[64][64];       // [d][key]
  __shared__ __align__(16) u16 Ps[4][16][64];    // per-wave P [qrow][key]
  const float C = 0.125f * 1.44269504f;          // 1/sqrt(64) * log2(e)
  int tid = threadIdx.x;
  int lane = tid & 63, w = tid >> 6;
  int lr = lane & 15, lg = lane >> 4;
  int bh = blockIdx.x >> 5, qt = blockIdx.x & 31;
  int b = bh >> 3, h = bh & 7;
  size_t qrow0 = (size_t)(b * 2048 + qt * 64 + w * 16);

  // Q fragments in registers: wave owns 16 q-rows (A-frag: lane holds Q[lr][lg*8+j])
  bf16x8 qf[2];
#pragma unroll
  for (int kf = 0; kf < 2; ++kf)
    qf[kf] = *(const bf16x8*)&q[(qrow0 + lr) * 512 + h * 64 + kf * 32 + lg * 8];

  f32x4 oacc[4];
#pragma unroll
  for (int j = 0; j < 4; ++j) {
    f32x4 zf = {0.f, 0.f, 0.f, 0.f};
    oacc[j] = zf;
  }
  float mrow[4], lrow[4];
#pragma unroll
  for (int r = 0; r < 4; ++r) { mrow[r] = -1e30f; lrow[r] = 0.f; }

  const u16* kbase = kmat + (size_t)(b * 2048) * 512 + h * 64;
  const u16* vbase = vT + (size_t)(bh * 64) * 2048;

  for (int kt = 0; kt < 32; ++kt) {
    // stage K tile [64 keys][64 d] and V tile [64 d][64 keys], swizzled
#pragma unroll
    for (int i = 0; i < 2; ++i) {
      int idx = i * 256 + tid;
      int row = idx >> 3, c8 = idx & 7;
      int sc = (c8 * 8) ^ ((row & 7) << 3);
      *(uint4*)&Ks[row][sc] = *(const uint4*)&kbase[(size_t)(kt * 64 + row) * 512 + c8 * 8];
      *(uint4*)&Vs[row][sc] = *(const uint4*)&vbase[(size_t)row * 2048 + kt * 64 + c8 * 8];
    }
    __syncthreads();

    // S = Q @ K^T : S[q=lg*4+r][key=nf*16+lr] in sacc[nf][r]
    f32x4 sacc[4];
#pragma unroll
    for (int j = 0; j < 4; ++j) {
      f32x4 zf = {0.f, 0.f, 0.f, 0.f};
      sacc[j] = zf;
    }
#pragma unroll
    for (int kf = 0; kf < 2; ++kf) {
#pragma unroll
      for (int nf = 0; nf < 4; ++nf) {
        int row = nf * 16 + lr;
        bf16x8 kb = *(const bf16x8*)&Ks[row][(kf * 32 + lg * 8) ^ ((row & 7) << 3)];
        sacc[nf] = mfma16(qf[kf], kb, sacc[nf]);
      }
    }

    // online softmax: each lane-group (lg) owns rows lg*4+r, stats shared over lr lanes
#pragma unroll
    for (int r = 0; r < 4; ++r) {
      float mx = fmaxf(fmaxf(sacc[0][r], sacc[1][r]), fmaxf(sacc[2][r], sacc[3][r]));
      mx = fmaxf(mx, __shfl_xor(mx, 1));
      mx = fmaxf(mx, __shfl_xor(mx, 2));
      mx = fmaxf(mx, __shfl_xor(mx, 4));
      mx = fmaxf(mx, __shfl_xor(mx, 8));
      float mnew = fmaxf(mrow[r], mx);
      float sc = __builtin_amdgcn_exp2f((mrow[r] - mnew) * C);
      mrow[r] = mnew;
      int qloc = lg * 4 + r;
      int sw = (qloc & 7) << 3;
      u16* prow = &Ps[w][qloc][0];
      float rsum = 0.f;
#pragma unroll
      for (int nf = 0; nf < 4; ++nf) {
        float p = __builtin_amdgcn_exp2f((sacc[nf][r] - mnew) * C);
        rsum += p;
        prow[(nf * 16 + lr) ^ sw] = f2bf(p);
      }
      rsum += __shfl_xor(rsum, 1);
      rsum += __shfl_xor(rsum, 2);
      rsum += __shfl_xor(rsum, 4);
      rsum += __shfl_xor(rsum, 8);
      lrow[r] = lrow[r] * sc + rsum;
#pragma unroll
      for (int nfo = 0; nfo < 4; ++nfo) oacc[nfo][r] *= sc;
    }

    // O += P @ V  (A-frag: lane reads P[lr][lg*8+j]; B-frag: V^T[d=nfo*16+lr][keys])
#pragma unroll
    for (int ks = 0; ks < 2; ++ks) {
      bf16x8 pa = *(const bf16x8*)&Ps[w][lr][(ks * 32 + lg * 8) ^ ((lr & 7) << 3)];
#pragma unroll
      for (int nfo = 0; nfo < 4; ++nfo) {
        int row = nfo * 16 + lr;
        bf16x8 vb = *(const bf16x8*)&Vs[row][(ks * 32 + lg * 8) ^ ((row & 7) << 3)];
        oacc[nfo] = mfma16(pa, vb, oacc[nfo]);
      }
    }
    __syncthreads();
  }

  // normalize + store z (bf16, [B*S][512])
  float rl[4];
#pragma unroll
  for (int r = 0; r < 4; ++r) rl[r] = 1.f / lrow[r];
#pragma unroll
  for (int nfo = 0; nfo < 4; ++nfo)
#pragma unroll
    for (int r = 0; r < 4; ++r)
      z[(qrow0 + lg * 4 + r) * 512 + h * 64 + nfo * 16 + lr] = f2bf(oacc[nfo][r] * rl[r]);
}

extern "C" void kernel_launch(void* const* d_in, const int* in_sizes, int n_in,
                              void* d_out, int out_size, void* d_ws, size_t ws_size,
                              hipStream_t stream) {
  const float* Q  = (const float*)d_in[0];
  const float* K  = (const float*)d_in[1];
  const float* V  = (const float*)d_in[2];
  const float* Wq = (const float*)d_in[3];
  const float* bq = (const float*)d_in[4];
  const float* Wk = (const float*)d_in[5];
  const float* bk = (const float*)d_in[6];
  const float* Wv = (const float*)d_in[7];
  const float* bv = (const float*)d_in[8];
  const float* Wo = (const float*)d_in[9];
  const float* bo = (const float*)d_in[10];
  float* out = (float*)d_out;

  // workspace layout (34 MB total, all bf16/u16):
  u16* ws  = (u16*)d_ws;
  u16* Wtq = ws;                                   // 512*512 each
  u16* Wtk = Wtq + 512 * 512;
  u16* Wtv = Wtk + 512 * 512;
  u16* Wto = Wtv + 512 * 512;
  u16* qws = Wto + 512 * 512;                      // 8192*512 each
  u16* kws = qws + (size_t)8192 * 512;
  u16* vTw = kws + (size_t)8192 * 512;             // [(b*8+h)*64+d][2048]
  u16* zws = vTw + (size_t)8192 * 512;

  wtrans_k<<<1024, 256, 0, stream>>>(Wq, Wtq);
  wtrans_k<<<1024, 256, 0, stream>>>(Wk, Wtk);
  wtrans_k<<<1024, 256, 0, stream>>>(Wv, Wtv);
  wtrans_k<<<1024, 256, 0, stream>>>(Wo, Wto);

  gemm_k<false, 0><<<256, 256, 0, stream>>>(Q, Wtq, bq, qws);
  gemm_k<false, 0><<<256, 256, 0, stream>>>(K, Wtk, bk, kws);
  gemm_k<false, 1><<<256, 256, 0, stream>>>(V, Wtv, bv, vTw);

  attn_k<<<1024, 256, 0, stream>>>(qws, kws, vTw, zws);

  gemm_k<true, 2><<<256, 256, 0, stream>>>(zws, Wto, bo, out);
}